// Round 1
// baseline (244.502 us; speedup 1.0000x reference)
//
#include <hip/hip_runtime.h>
#include <math.h>

#define KTR 96
#define DIM 256
#define PB  40
#define CH  8
#define MDIM (KTR*PB)   // 3840

#define BM 128
#define BN 80
#define BK 32
#define AS 132   // As[d][m] row stride (pad 4: keeps 16B alignment, 4-way write conflict only on staging)
#define BS 85    // Bs[d][n] row stride (odd pad: conflict-free scalar access)

// ---------------- Kernel 1: L2-normalize over D, store transposed [d][m] ----------------
__global__ __launch_bounds__(256) void k_norm(const float* __restrict__ enroll,
                                              const float* __restrict__ test,
                                              float* __restrict__ eT,
                                              float* __restrict__ tT) {
    int b = blockIdx.x;
    int k = (b < KTR) ? b : b - KTR;
    const float* src = (b < KTR) ? (enroll + (size_t)k * DIM * PB)
                                 : (test   + (size_t)k * DIM * PB);
    float* dst = (b < KTR) ? eT : tT;

    __shared__ float part[6 * PB];
    __shared__ float rn[PB];
    int tid = threadIdx.x;

    if (tid < 240) {
        int g = tid / PB, p = tid - (tid / PB) * PB;
        float acc = 0.f;
        for (int d = g; d < DIM; d += 6) {
            float x = src[d * PB + p];
            acc = fmaf(x, x, acc);
        }
        part[g * PB + p] = acc;
    }
    __syncthreads();
    if (tid < PB) {
        float s = 0.f;
        #pragma unroll
        for (int g = 0; g < 6; ++g) s += part[g * PB + tid];
        rn[tid] = 1.0f / fmaxf(sqrtf(s), 1e-12f);
    }
    __syncthreads();
    // dst[d*MDIM + k*PB + p] = src[d*PB + p] * rn[p]
    for (int f = tid; f < DIM * PB; f += 256) {
        int d = f / PB, p = f - d * PB;
        dst[(size_t)d * MDIM + k * PB + p] = src[f] * rn[p];
    }
}

// ---------------- Kernel 2: fused GEMM (fp32) + gate + j-reduction ----------------
__global__ __launch_bounds__(256) void k_gemm(const float* __restrict__ eT,
                                              const float* __restrict__ tT,
                                              const float* __restrict__ fc1_w,
                                              const float* __restrict__ fc1_b,
                                              const float* __restrict__ fc2_w,
                                              float* __restrict__ pho2) {
    __shared__ __align__(16) float As[BK * AS];
    __shared__ __align__(16) float Bs[BK * BS];

    int tid = threadIdx.x;
    int m0 = blockIdx.y * BM;
    int n0 = blockIdx.x * BN;
    int tn = tid & 15;        // 16 threads along N, 5 cols each
    int tm = tid >> 4;        // 16 threads along M, 8 rows each

    float acc[8][5];
    #pragma unroll
    for (int i = 0; i < 8; ++i)
        #pragma unroll
        for (int q = 0; q < 5; ++q) acc[i][q] = 0.f;

    int a_m4 = tid & 31;      // float4 index along M (0..31)
    int a_d  = tid >> 5;      // 0..7

    for (int d0 = 0; d0 < DIM; d0 += BK) {
        // stage A: 32 d-rows x 128 m (1024 float4 / 256 threads)
        #pragma unroll
        for (int it = 0; it < 4; ++it) {
            int dd = a_d + it * 8;
            const float4 v = *(const float4*)(eT + (size_t)(d0 + dd) * MDIM + m0 + a_m4 * 4);
            *(float4*)(&As[dd * AS + a_m4 * 4]) = v;
        }
        // stage B: 32 d-rows x 80 n (1280 float2 / 256 threads)
        #pragma unroll
        for (int it = 0; it < 5; ++it) {
            int f = tid + it * 256;
            int dd = f / 40, nn2 = f - dd * 40;
            const float2 v = *(const float2*)(tT + (size_t)(d0 + dd) * MDIM + n0 + nn2 * 2);
            Bs[dd * BS + nn2 * 2]     = v.x;
            Bs[dd * BS + nn2 * 2 + 1] = v.y;
        }
        __syncthreads();

        #pragma unroll
        for (int d = 0; d < BK; ++d) {
            float4 a0 = *(const float4*)(&As[d * AS + tm * 8]);
            float4 a1 = *(const float4*)(&As[d * AS + tm * 8 + 4]);
            float av[8] = {a0.x, a0.y, a0.z, a0.w, a1.x, a1.y, a1.z, a1.w};
            float bv[5];
            #pragma unroll
            for (int q = 0; q < 5; ++q) bv[q] = Bs[d * BS + tn * 5 + q];
            #pragma unroll
            for (int i = 0; i < 8; ++i)
                #pragma unroll
                for (int q = 0; q < 5; ++q)
                    acc[i][q] = fmaf(av[i], bv[q], acc[i][q]);
        }
        __syncthreads();
    }

    // gate params (uniform -> scalar loads)
    float w[CH], bb[CH], v2[CH];
    #pragma unroll
    for (int c = 0; c < CH; ++c) { w[c] = fc1_w[c]; bb[c] = fc1_b[c]; v2[c] = fc2_w[c]; }

    // this thread's 5 cols all lie in one phoneme group: lg = tn>>3
    int l = n0 / PB + (tn >> 3);

    #pragma unroll
    for (int r = 0; r < 8; ++r) {
        int m = m0 + tm * 8 + r;
        float s = 0.f, cnt = 0.f;
        #pragma unroll
        for (int q = 0; q < 5; ++q) {
            float x = acc[r][q];
            float g = 0.f;
            #pragma unroll
            for (int c = 0; c < CH; ++c) g = fmaf(v2[c], tanhf(fmaf(w[c], x, bb[c])), g);
            s = fmaf(g, x, s);
            cnt += (x != 0.0f) ? 1.0f : 0.0f;
        }
        // reduce across the 8 lanes covering one (row, l) group
        #pragma unroll
        for (int off = 4; off; off >>= 1) {
            s   += __shfl_down(s, off, 8);
            cnt += __shfl_down(cnt, off, 8);
        }
        if ((tn & 7) == 0) {
            int k = m / PB, i = m - k * PB;
            pho2[((size_t)k * KTR + l) * PB + i] = s / (cnt + 1e-6f);
        }
    }
}

// ---------------- Kernel 3: gate + i-reduction -> [K,K] ----------------
__global__ __launch_bounds__(256) void k_final(const float* __restrict__ pho2,
                                               const float* __restrict__ fc1_w,
                                               const float* __restrict__ fc1_b,
                                               const float* __restrict__ fc2_w,
                                               float* __restrict__ out) {
    int wv = threadIdx.x >> 6;
    int lane = threadIdx.x & 63;
    int pair = blockIdx.x * 4 + wv;   // 0..9215

    float w[CH], bb[CH], v2[CH];
    #pragma unroll
    for (int c = 0; c < CH; ++c) { w[c] = fc1_w[c]; bb[c] = fc1_b[c]; v2[c] = fc2_w[c]; }

    float x = (lane < PB) ? pho2[(size_t)pair * PB + lane] : 0.f;
    float g = 0.f;
    #pragma unroll
    for (int c = 0; c < CH; ++c) g = fmaf(v2[c], tanhf(fmaf(w[c], x, bb[c])), g);
    float s = g * x;                                  // lanes >= PB: x==0 -> 0
    float cnt = (lane < PB && x != 0.0f) ? 1.0f : 0.0f;

    #pragma unroll
    for (int off = 32; off; off >>= 1) {
        s   += __shfl_xor(s, off);
        cnt += __shfl_xor(cnt, off);
    }
    if (lane == 0) out[pair] = s / (cnt + 1e-6f);
}

extern "C" void kernel_launch(void* const* d_in, const int* in_sizes, int n_in,
                              void* d_out, int out_size, void* d_ws, size_t ws_size,
                              hipStream_t stream) {
    const float* enroll = (const float*)d_in[0];
    const float* test   = (const float*)d_in[1];
    const float* fc1_w  = (const float*)d_in[2];
    const float* fc1_b  = (const float*)d_in[3];
    const float* fc2_w  = (const float*)d_in[4];
    float* out = (float*)d_out;

    float* eT   = (float*)d_ws;                       // [DIM][MDIM]
    float* tT   = eT + (size_t)DIM * MDIM;            // [DIM][MDIM]
    float* pho2 = tT + (size_t)DIM * MDIM;            // [KTR*KTR*PB]

    k_norm<<<2 * KTR, 256, 0, stream>>>(enroll, test, eT, tT);
    dim3 g2(MDIM / BN, MDIM / BM);                    // (48, 30)
    k_gemm<<<g2, 256, 0, stream>>>(eT, tT, fc1_w, fc1_b, fc2_w, pho2);
    k_final<<<KTR * KTR / 4, 256, 0, stream>>>(pho2, fc1_w, fc1_b, fc2_w, out);
}

// Round 2
// 147.999 us; speedup vs baseline: 1.6521x; 1.6521x over previous
//
#include <hip/hip_runtime.h>
#include <math.h>

#define KTR 96
#define DIM 256
#define PB  40
#define CH  8
#define MDIM 3840
#define KK  512          // [hi(256) | lo*4096(256)] for A;  [lo*4096 | hi] for B
#define BM 128
#define BN 160
#define BK 32
#define LDA 40           // f16 elems per LDS row (32 + 8 pad -> 80B stride, conflict-uniform)
#define NTAB 2112        // intervals, h = 2^-10, range [-1.03125, 1.03125)

typedef _Float16 v8h __attribute__((ext_vector_type(8)));
typedef float    v4f __attribute__((ext_vector_type(4)));

// ---------------- Kernel 1: L2-normalize over D, emit f16 hi/lo split, [m][k] layout ----------------
__global__ __launch_bounds__(256) void k_norm(const float* __restrict__ enroll,
                                              const float* __restrict__ test,
                                              _Float16* __restrict__ XA,
                                              _Float16* __restrict__ XB) {
    int b = blockIdx.x;
    bool isE = (b < KTR);
    int k = isE ? b : b - KTR;
    const float* src = (isE ? enroll : test) + (size_t)k * DIM * PB;

    __shared__ float part[6 * PB];
    __shared__ float rn[PB];
    int tid = threadIdx.x;

    if (tid < 240) {
        int g = tid / PB, p = tid - (tid / PB) * PB;
        float acc = 0.f;
        for (int d = g; d < DIM; d += 6) {
            float x = src[d * PB + p];
            acc = fmaf(x, x, acc);
        }
        part[g * PB + p] = acc;
    }
    __syncthreads();
    if (tid < PB) {
        float s = 0.f;
        #pragma unroll
        for (int g = 0; g < 6; ++g) s += part[g * PB + tid];
        rn[tid] = 1.0f / fmaxf(sqrtf(s), 1e-12f);
    }
    __syncthreads();

    // tid == d (0..255); writes coalesced 2B stores along k
    for (int p = 0; p < PB; ++p) {
        float v = src[tid * PB + p] * rn[p];
        _Float16 h  = (_Float16)v;
        _Float16 lo = (_Float16)((v - (float)h) * 4096.0f);  // scaled: stays f16-normal
        size_t m = (size_t)(k * PB + p);
        if (isE) { XA[m * KK + tid] = h;  XA[m * KK + 256 + tid] = lo; }
        else     { XB[m * KK + tid] = lo; XB[m * KK + 256 + tid] = h;  }
    }
}

// ---------------- Kernel 2: split-f16 MFMA GEMM + LDS-table gate + j-reduction ----------------
__global__ __launch_bounds__(256) void k_gemm(const _Float16* __restrict__ XA,
                                              const _Float16* __restrict__ XB,
                                              const float* __restrict__ fc1_w,
                                              const float* __restrict__ fc1_b,
                                              const float* __restrict__ fc2_w,
                                              float* __restrict__ pho2) {
    __shared__ __align__(16) _Float16 LA[BM * LDA];   // 10240 B
    __shared__ __align__(16) _Float16 LB[BN * LDA];   // 12800 B
    __shared__ float2 gtab[NTAB + 1];                 // 16904 B  (value, delta-per-interval)

    int tid  = threadIdx.x;
    int lane = tid & 63;
    int wv   = tid >> 6;

    // ---- build gate table: g(x) = sum_c v2_c * tanh(w_c x + b_c), x_i = (i-1056)/1024 ----
    {
        float w[CH], bb[CH], v2[CH];
        #pragma unroll
        for (int c = 0; c < CH; ++c) { w[c] = fc1_w[c]; bb[c] = fc1_b[c]; v2[c] = fc2_w[c]; }
        for (int i = tid; i < NTAB + 1; i += 256) {
            float x = (float)(i - 1056) * 0.0009765625f;
            float g = 0.f;
            #pragma unroll
            for (int c = 0; c < CH; ++c) g = fmaf(v2[c], tanhf(fmaf(w[c], x, bb[c])), g);
            gtab[i].x = g;
        }
    }
    __syncthreads();
    for (int i = tid; i < NTAB; i += 256) gtab[i].y = gtab[i + 1].x - gtab[i].x;
    // slope writes are covered by the first k-loop barrier before any gate read

    int m0 = blockIdx.y * BM;
    int n0 = blockIdx.x * BN;
    int wm = (wv & 1) * 64;
    int wn = (wv >> 1) * 80;
    int r15 = lane & 15;
    int q4  = lane >> 4;

    v4f acc[4][5];
    #pragma unroll
    for (int mt = 0; mt < 4; ++mt)
        #pragma unroll
        for (int nt = 0; nt < 5; ++nt)
            acc[mt][nt] = (v4f)0.f;

    // fragment LDS element offsets
    int aoff[4], boff[5];
    #pragma unroll
    for (int mt = 0; mt < 4; ++mt) aoff[mt] = (wm + mt * 16 + r15) * LDA + q4 * 8;
    #pragma unroll
    for (int nt = 0; nt < 5; ++nt) boff[nt] = (wn + nt * 16 + r15) * LDA + q4 * 8;

    // staging pointers (16B chunks); A: 512 chunks (2/thread), B: 640 chunks (2.5/thread)
    int arow = tid >> 2, aqc = tid & 3;
    const uint4* gA = (const uint4*)(XA + (size_t)(m0 + arow) * KK) + aqc;
    const uint4* gB = (const uint4*)(XB + (size_t)(n0 + arow) * KK) + aqc;
    uint4* lA = (uint4*)LA + (arow * 5 + aqc);        // LDA elems = 5 uint4 per row
    uint4* lB = (uint4*)LB + (arow * 5 + aqc);

    for (int it = 0; it < 24; ++it) {
        int ka = (it < 16) ? (it * BK) : ((it - 16) * BK);          // A: hi|lo' then hi
        int kb = (it < 16) ? (it * BK) : (256 + (it - 16) * BK);    // B: lo'|hi then hi
        int ia = ka >> 3, ib = kb >> 3;                             // uint4 offset within row
        uint4 va0 = gA[ia];
        uint4 va1 = gA[ia + 64 * (KK / 8)];                         // +64 rows
        uint4 vb0 = gB[ib];
        uint4 vb1 = gB[ib + 64 * (KK / 8)];
        uint4 vb2;
        if (tid < 128) vb2 = gB[ib + 128 * (KK / 8)];
        __syncthreads();                                            // prev iter's MFMAs done
        lA[0]   = va0;
        lA[320] = va1;                                              // +64 rows * 5
        lB[0]   = vb0;
        lB[320] = vb1;
        if (tid < 128) lB[640] = vb2;
        __syncthreads();

        if (it == 16) {                                             // cross done: scale by 2^-12 (exact)
            #pragma unroll
            for (int mt = 0; mt < 4; ++mt)
                #pragma unroll
                for (int nt = 0; nt < 5; ++nt)
                    acc[mt][nt] *= 0.000244140625f;
        }

        v8h af[4], bf[5];
        #pragma unroll
        for (int mt = 0; mt < 4; ++mt) af[mt] = *(const v8h*)(LA + aoff[mt]);
        #pragma unroll
        for (int nt = 0; nt < 5; ++nt) bf[nt] = *(const v8h*)(LB + boff[nt]);
        #pragma unroll
        for (int mt = 0; mt < 4; ++mt)
            #pragma unroll
            for (int nt = 0; nt < 5; ++nt)
                acc[mt][nt] = __builtin_amdgcn_mfma_f32_16x16x32_f16(af[mt], bf[nt], acc[mt][nt], 0, 0, 0);
    }

    // ---- epilogue: table gate, j-sum within wave, store pho2[k,l,i] ----
    #pragma unroll
    for (int mt = 0; mt < 4; ++mt) {
        float s[2][4];
        #pragma unroll
        for (int g = 0; g < 2; ++g)
            #pragma unroll
            for (int r = 0; r < 4; ++r) s[g][r] = 0.f;

        #pragma unroll
        for (int nt = 0; nt < 5; ++nt) {
            int col = nt * 16 + r15;
            int grp = (col >= 40) ? 1 : 0;
            #pragma unroll
            for (int r = 0; r < 4; ++r) {
                float x = acc[mt][nt][r];
                float u = fmaf(x, 1024.0f, 1056.0f);
                int i = (int)u;
                i = min(max(i, 0), NTAB - 1);
                float f = u - (float)i;
                float2 tv = gtab[i];
                float g = fmaf(f, tv.y, tv.x);
                s[grp][r] = fmaf(g, x, s[grp][r]);
            }
        }
        #pragma unroll
        for (int off = 1; off < 16; off <<= 1)
            #pragma unroll
            for (int g = 0; g < 2; ++g)
                #pragma unroll
                for (int r = 0; r < 4; ++r)
                    s[g][r] += __shfl_xor(s[g][r], off);

        if (r15 == 0) {
            int lbase = (n0 + wn) / PB;
            #pragma unroll
            for (int r = 0; r < 4; ++r) {
                int m = m0 + wm + mt * 16 + q4 * 4 + r;
                int kt = m / PB, ii = m - kt * PB;
                #pragma unroll
                for (int g = 0; g < 2; ++g)
                    pho2[((size_t)kt * KTR + (lbase + g)) * PB + ii] = s[g][r] / (40.0f + 1e-6f);
            }
        }
    }
}

// ---------------- Kernel 3: gate + i-reduction -> [K,K] ----------------
__global__ __launch_bounds__(256) void k_final(const float* __restrict__ pho2,
                                               const float* __restrict__ fc1_w,
                                               const float* __restrict__ fc1_b,
                                               const float* __restrict__ fc2_w,
                                               float* __restrict__ out) {
    int wv = threadIdx.x >> 6;
    int lane = threadIdx.x & 63;
    int pair = blockIdx.x * 4 + wv;   // 0..9215

    float w[CH], bb[CH], v2[CH];
    #pragma unroll
    for (int c = 0; c < CH; ++c) { w[c] = fc1_w[c]; bb[c] = fc1_b[c]; v2[c] = fc2_w[c]; }

    float x = (lane < PB) ? pho2[(size_t)pair * PB + lane] : 0.f;
    float g = 0.f;
    #pragma unroll
    for (int c = 0; c < CH; ++c) g = fmaf(v2[c], tanhf(fmaf(w[c], x, bb[c])), g);
    float s = g * x;

    #pragma unroll
    for (int off = 32; off; off >>= 1) s += __shfl_xor(s, off);
    if (lane == 0) out[pair] = s / (40.0f + 1e-6f);
}

extern "C" void kernel_launch(void* const* d_in, const int* in_sizes, int n_in,
                              void* d_out, int out_size, void* d_ws, size_t ws_size,
                              hipStream_t stream) {
    const float* enroll = (const float*)d_in[0];
    const float* test   = (const float*)d_in[1];
    const float* fc1_w  = (const float*)d_in[2];
    const float* fc1_b  = (const float*)d_in[3];
    const float* fc2_w  = (const float*)d_in[4];
    float* out = (float*)d_out;

    _Float16* XA = (_Float16*)d_ws;                    // [3840][512] f16
    _Float16* XB = XA + (size_t)MDIM * KK;             // [3840][512] f16
    float* pho2  = (float*)(XB + (size_t)MDIM * KK);   // [96*96*40] f32

    k_norm<<<2 * KTR, 256, 0, stream>>>(enroll, test, XA, XB);
    dim3 g2(MDIM / BN, MDIM / BM);                     // (24, 30)
    k_gemm<<<g2, 256, 0, stream>>>(XA, XB, fc1_w, fc1_b, fc2_w, pho2);
    k_final<<<KTR * KTR / 4, 256, 0, stream>>>(pho2, fc1_w, fc1_b, fc2_w, out);
}

// Round 3
// 111.990 us; speedup vs baseline: 2.1832x; 1.3215x over previous
//
#include <hip/hip_runtime.h>
#include <math.h>

#define KTR 96
#define DIM 256
#define PB  40
#define CH  8
#define MDIM 3840
#define KK  512          // [hi | lo*4096] for XT (test/M);  [lo*4096 | hi] for XE (enroll/N)
#define BM 160           // M-tile (test rows: l,j) = 4 phoneme groups
#define BN 128           // N-tile (enroll cols: k,i)
#define BK 32
#define LDA 40           // f16 elems per LDS row (32 + 8 pad)
#define NTAB 2113        // table nodes, h = 2^-10, x = (i-1056)/1024
#define TPAD 2120

typedef _Float16 v8h __attribute__((ext_vector_type(8)));
typedef float    v4f __attribute__((ext_vector_type(4)));

__device__ __forceinline__ float gate_ref(float x, const float* w, const float* b, const float* v) {
    float g = 0.f;
    #pragma unroll
    for (int c = 0; c < CH; ++c) g = fmaf(v[c], tanhf(fmaf(w[c], x, b[c])), g);
    return g;
}

// ---------------- Kernel 1: L2-normalize + f16 hi/lo split + (extra blocks) gate table ----------------
__global__ __launch_bounds__(256) void k_norm(const float* __restrict__ enroll,
                                              const float* __restrict__ test,
                                              const float* __restrict__ fc1_w,
                                              const float* __restrict__ fc1_b,
                                              const float* __restrict__ fc2_w,
                                              _Float16* __restrict__ XT,
                                              _Float16* __restrict__ XE,
                                              float2* __restrict__ gtabG) {
    int b = blockIdx.x, tid = threadIdx.x;

    if (b >= 2 * KTR) {                       // 9 table-builder blocks
        int i = (b - 2 * KTR) * 256 + tid;
        if (i < NTAB) {
            float w[CH], bb[CH], vv[CH];
            #pragma unroll
            for (int c = 0; c < CH; ++c) { w[c] = fc1_w[c]; bb[c] = fc1_b[c]; vv[c] = fc2_w[c]; }
            float g0 = gate_ref((float)(i - 1056) * 0.0009765625f, w, bb, vv);
            float g1 = gate_ref((float)(i - 1055) * 0.0009765625f, w, bb, vv);
            gtabG[i] = make_float2(g0, g1 - g0);
        }
        return;
    }

    bool isE = (b < KTR);
    int k = isE ? b : b - KTR;
    const float* src = (isE ? enroll : test) + (size_t)k * DIM * PB;

    __shared__ float S[DIM * 41];             // stride 41: conflict-free column walk
    __shared__ float part[6 * PB];
    __shared__ float rn[PB];

    // coalesced float4 stage
    for (int i = tid; i < DIM * PB / 4; i += 256) {
        float4 v = ((const float4*)src)[i];
        int d = i / 10, c = i - d * 10;
        float* p = &S[d * 41 + c * 4];
        p[0] = v.x; p[1] = v.y; p[2] = v.z; p[3] = v.w;
    }
    __syncthreads();
    if (tid < 240) {
        int g = tid / PB, p = tid - (tid / PB) * PB;
        float acc = 0.f;
        for (int d = g; d < DIM; d += 6) {
            float x = S[d * 41 + p];
            acc = fmaf(x, x, acc);
        }
        part[g * PB + p] = acc;
    }
    __syncthreads();
    if (tid < PB) {
        float s = 0.f;
        #pragma unroll
        for (int g = 0; g < 6; ++g) s += part[g * PB + tid];
        rn[tid] = 1.0f / fmaxf(sqrtf(s), 1e-12f);
    }
    __syncthreads();

    // tid == d; stores coalesced 2B along d
    int d = tid;
    for (int p = 0; p < PB; ++p) {
        float v = S[d * 41 + p] * rn[p];
        _Float16 h  = (_Float16)v;
        _Float16 lo = (_Float16)((v - (float)h) * 4096.0f);
        size_t m = (size_t)(k * PB + p);
        if (isE) { XE[m * KK + d] = lo; XE[m * KK + 256 + d] = h;  }
        else     { XT[m * KK + d] = h;  XT[m * KK + 256 + d] = lo; }
    }
}

// ---------------- Kernel 2: pipelined split-f16 MFMA GEMM + table gate + j-reduction ----------------
__global__ __launch_bounds__(256, 3) void k_gemm(const _Float16* __restrict__ XT,
                                                 const _Float16* __restrict__ XE,
                                                 const float2* __restrict__ gtabG,
                                                 float* __restrict__ pho2) {
    __shared__ __align__(16) _Float16 LA[BM * LDA];   // 12800 B  (test rows)
    __shared__ __align__(16) _Float16 LB[BN * LDA];   // 10240 B  (enroll rows)
    __shared__ float gval[TPAD];                      // split tables: b32 random ~2-way (free)
    __shared__ float gslope[TPAD];

    int tid  = threadIdx.x;
    int lane = tid & 63;
    int wv   = tid >> 6;

    for (int i = tid; i < NTAB; i += 256) {
        float2 t = gtabG[i];
        gval[i] = t.x; gslope[i] = t.y;
    }

    int m0 = blockIdx.y * BM;
    int n0 = blockIdx.x * BN;
    int wm = (wv & 1) * 80;
    int wn = (wv >> 1) * 64;
    int r15 = lane & 15;
    int q4  = lane >> 4;

    v4f acc[5][4];
    #pragma unroll
    for (int mt = 0; mt < 5; ++mt)
        #pragma unroll
        for (int nt = 0; nt < 4; ++nt)
            acc[mt][nt] = (v4f)0.f;

    int aoff[5], boff[4];
    #pragma unroll
    for (int mt = 0; mt < 5; ++mt) aoff[mt] = (wm + mt * 16 + r15) * LDA + q4 * 8;
    #pragma unroll
    for (int nt = 0; nt < 4; ++nt) boff[nt] = (wn + nt * 16 + r15) * LDA + q4 * 8;

    int arow = tid >> 2, aqc = tid & 3;               // 64 rows x 4 chunks
    const uint4* gT = (const uint4*)(XT + (size_t)(m0 + arow) * KK);  // 64 uint4 per row
    const uint4* gE = (const uint4*)(XE + (size_t)(n0 + arow) * KK);
    uint4* lA = (uint4*)LA + (arow * 5 + aqc);
    uint4* lB = (uint4*)LB + (arow * 5 + aqc);

    uint4 va0, va1, va2, vb0, vb1;
    #define LOADS(IT) {                                                     \
        int ka = ((IT) < 16) ? (IT) * BK : ((IT) - 16) * BK;                \
        int kb = ((IT) < 16) ? (IT) * BK : 256 + ((IT) - 16) * BK;          \
        int ia = (ka >> 3) + aqc, ib = (kb >> 3) + aqc;                     \
        va0 = gT[ia]; va1 = gT[ia + 64 * 64];                               \
        if (tid < 128) va2 = gT[ia + 128 * 64];                             \
        vb0 = gE[ib]; vb1 = gE[ib + 64 * 64]; }

    LOADS(0);
    for (int it = 0; it < 24; ++it) {
        __syncthreads();                               // prev iter's frag reads done
        lA[0]   = va0;
        lA[320] = va1;                                 // +64 rows * 5 chunks
        if (tid < 128) lA[640] = va2;                  // rows 128..159
        lB[0]   = vb0;
        lB[320] = vb1;
        __syncthreads();

        if (it < 23) LOADS(it + 1);                    // prefetch overlaps MFMA below

        if (it == 16) {                                // cross terms done: scale by 2^-12 (exact)
            #pragma unroll
            for (int mt = 0; mt < 5; ++mt)
                #pragma unroll
                for (int nt = 0; nt < 4; ++nt)
                    acc[mt][nt] *= 0.000244140625f;
        }

        v8h af[5], bf[4];
        #pragma unroll
        for (int mt = 0; mt < 5; ++mt) af[mt] = *(const v8h*)(LA + aoff[mt]);
        #pragma unroll
        for (int nt = 0; nt < 4; ++nt) bf[nt] = *(const v8h*)(LB + boff[nt]);
        #pragma unroll
        for (int mt = 0; mt < 5; ++mt)
            #pragma unroll
            for (int nt = 0; nt < 4; ++nt)
                acc[mt][nt] = __builtin_amdgcn_mfma_f32_16x16x32_f16(af[mt], bf[nt], acc[mt][nt], 0, 0, 0);
    }
    #undef LOADS

    // ---- epilogue: D row = q4*4+r (test: l,j), col = r15 (enroll: k,i) ----
    const float inv40 = 1.0f / (40.0f + 1e-6f);
    int lg = (m0 + wm) / PB;                           // wave covers groups lg, lg+1
    #pragma unroll
    for (int nt = 0; nt < 4; ++nt) {
        float s0 = 0.f, s1 = 0.f, t2 = 0.f;
        #pragma unroll
        for (int mt = 0; mt < 5; ++mt) {
            #pragma unroll
            for (int r = 0; r < 4; ++r) {
                float x = acc[mt][nt][r];
                float u = fmaf(x, 1024.0f, 1056.0f);
                int i = (int)u;
                i = min(max(i, 0), NTAB - 2);
                float f = u - (float)i;
                float g = fmaf(f, gslope[i], gval[i]);
                float xg = g * x;
                if (mt < 2)       s0 += xg;            // rows 0..31  -> group lg
                else if (mt == 2) t2 += xg;            // rows 32..47 -> straddle
                else              s1 += xg;            // rows 48..79 -> group lg+1
            }
        }
        bool lo = (q4 < 2);                            // mt=2: q4<2 -> rows 32..39 (lg)
        s0 += lo ? t2 : 0.f;
        s1 += lo ? 0.f : t2;
        s0 += __shfl_xor(s0, 16); s0 += __shfl_xor(s0, 32);
        s1 += __shfl_xor(s1, 16); s1 += __shfl_xor(s1, 32);
        if (q4 == 0) {
            int n = n0 + wn + nt * 16 + r15;
            int kk = n / PB, ii = n - kk * PB;
            pho2[((size_t)kk * KTR + lg)     * PB + ii] = s0 * inv40;
            pho2[((size_t)kk * KTR + lg + 1) * PB + ii] = s1 * inv40;
        }
    }
}

// ---------------- Kernel 3: gate (full range -> tanhf) + i-reduction -> [K,K] ----------------
__global__ __launch_bounds__(256) void k_final(const float* __restrict__ pho2,
                                               const float* __restrict__ fc1_w,
                                               const float* __restrict__ fc1_b,
                                               const float* __restrict__ fc2_w,
                                               float* __restrict__ out) {
    int wv = threadIdx.x >> 6;
    int lane = threadIdx.x & 63;
    int pair = blockIdx.x * 4 + wv;

    float w[CH], bb[CH], vv[CH];
    #pragma unroll
    for (int c = 0; c < CH; ++c) { w[c] = fc1_w[c]; bb[c] = fc1_b[c]; vv[c] = fc2_w[c]; }

    float x = (lane < PB) ? pho2[(size_t)pair * PB + lane] : 0.f;
    float s = gate_ref(x, w, bb, vv) * x;

    #pragma unroll
    for (int off = 32; off; off >>= 1) s += __shfl_xor(s, off);
    if (lane == 0) out[pair] = s / (40.0f + 1e-6f);
}

extern "C" void kernel_launch(void* const* d_in, const int* in_sizes, int n_in,
                              void* d_out, int out_size, void* d_ws, size_t ws_size,
                              hipStream_t stream) {
    const float* enroll = (const float*)d_in[0];
    const float* test   = (const float*)d_in[1];
    const float* fc1_w  = (const float*)d_in[2];
    const float* fc1_b  = (const float*)d_in[3];
    const float* fc2_w  = (const float*)d_in[4];
    float* out = (float*)d_out;

    _Float16* XT = (_Float16*)d_ws;                    // [3840][512] f16 (test:  hi|lo')
    _Float16* XE = XT + (size_t)MDIM * KK;             // [3840][512] f16 (enroll: lo'|hi)
    float* pho2  = (float*)(XE + (size_t)MDIM * KK);   // [96*96*40] f32
    float2* gtabG = (float2*)(pho2 + (size_t)KTR * KTR * PB);

    k_norm<<<2 * KTR + 9, 256, 0, stream>>>(enroll, test, fc1_w, fc1_b, fc2_w, XT, XE, gtabG);
    dim3 g2(MDIM / BN, MDIM / BM);                     // (30, 24)
    k_gemm<<<g2, 256, 0, stream>>>(XT, XE, gtabG, pho2);
    k_final<<<KTR * KTR / 4, 256, 0, stream>>>(pho2, fc1_w, fc1_b, fc2_w, out);
}